// Round 7
// baseline (220.727 us; speedup 1.0000x reference)
//
#include <hip/hip_runtime.h>
#include <hip/hip_bf16.h>

// B=256, IN=512, OUT=512
//   y_mean = x_mean @ A_mean + b_mean
//   y_var  = diag_embed( (diag(x_var)+x_mean^2) @ A_var + diag(A^T Cov A) + b_var )
// term2[b,o] = sum_i A[i,o] * (x_var[b] @ A)[i,o]  -> stacked GEMM + weighted colsum
//
// k_gemm2: double-buffered BK=32 pipeline with COUNTED vmcnt (T4): per iter
//   stage(next) -> s_waitcnt vmcnt(6) -> raw s_barrier -> compute(cur) -> s_barrier
// so prefetch loads stay in flight across barriers (never drained to 0 in-loop).
// X staged f32 via global_load_lds w/ pre-XOR-swizzled sources; f32->bf16 at
// fragment load. A pre-imaged bf16 (paired-row superrows, 8-chunk XOR swizzle).

typedef __bf16 bf16x8 __attribute__((ext_vector_type(8)));
typedef float f32x4 __attribute__((ext_vector_type(4)));

__device__ inline ushort f2bf(float f) {
    union { float f; unsigned u; } x; x.f = f;
    unsigned u = x.u + 0x7fffu + ((x.u >> 16) & 1u);   // RNE
    return (ushort)(u >> 16);
}

__device__ inline void gload16(const void* g, void* l) {
    __builtin_amdgcn_global_load_lds(
        (const __attribute__((address_space(1))) void*)g,
        (__attribute__((address_space(3))) void*)l, 16, 0, 0);
}

// ---- kernel 1: A_mean -> bf16 A^T images for BK=32, paired-row superrows ----
// Image layout per nt (128KB): [ks=16][superrow s=64][chunk c=8][8 bf16]
//   lc = c ^ (s&7); h = lc>>2; g = lc&3; row r = 2s+h; o = nt*128+r;
//   value[e] = A[ks*32 + g*8 + e][o]
__global__ void k_prep_at(const float* __restrict__ am, ushort* __restrict__ abt) {
    int C = blockIdx.x * 256 + threadIdx.x;   // chunk id 0..32767
    int nt = C >> 13;
    int L  = C & 8191;
    int ks = L >> 9;
    int rem = L & 511;
    int s = rem >> 3, c = rem & 7;
    int lc = c ^ (s & 7);
    int h = lc >> 2, g = lc & 3;
    int r = 2 * s + h;
    int o = nt * 128 + r;
    int j0 = ks * 32 + g * 8;
    ushort u[8];
    #pragma unroll
    for (int e = 0; e < 8; ++e) u[e] = f2bf(am[(j0 + e) * 512 + o]);
    *(int4*)(abt + (long)C * 8) = *(int4*)u;
}

// ---- kernel 2: xx[b][i] = x_var[b,i,i] + x_mean^2 ----
__global__ void k_diag(const float* __restrict__ xv, const float* __restrict__ xm,
                       float* __restrict__ xx) {
    int idx = blockIdx.x * 256 + threadIdx.x;     // b*512+i
    int b = idx >> 9, i = idx & 511;
    float m = xm[idx];
    xx[idx] = xv[(long)b * 262144 + i * 513] + m * m;
}

// ---- kernel 3: partial small GEMMs: yp/tp[ic][b][o] over 64-i chunks ----
__global__ void k_t1(const float* __restrict__ xm, const float* __restrict__ xx,
                     const float* __restrict__ am, const float* __restrict__ av,
                     float* __restrict__ yp, float* __restrict__ tp) {
    __shared__ float S[2][64];
    int t = threadIdx.x;
    int b  = blockIdx.x >> 3;
    int ic = blockIdx.x & 7;
    int i0 = ic * 64;
    if (t < 128) {
        int which = t >> 6, ii = t & 63;
        const float* src = which ? xx : xm;
        S[which][ii] = src[b * 512 + i0 + ii];
    }
    __syncthreads();
    int mat = t >> 7;                 // wave-uniform: 0 -> am/ym, 1 -> av/t1
    int o4 = t & 127;
    const float* M = mat ? av : am;
    const float* Sv = S[mat];
    f32x4 acc = {0.f, 0.f, 0.f, 0.f};
    #pragma unroll 8
    for (int ii = 0; ii < 64; ++ii) {
        f32x4 a = *(const f32x4*)(M + (long)(i0 + ii) * 512 + o4 * 4);
        float s = Sv[ii];
        acc[0] = fmaf(s, a[0], acc[0]);
        acc[1] = fmaf(s, a[1], acc[1]);
        acc[2] = fmaf(s, a[2], acc[2]);
        acc[3] = fmaf(s, a[3], acc[3]);
    }
    float* dst = (mat ? tp : yp) + ((long)ic * 256 + b) * 512 + o4 * 4;
    *(f32x4*)dst = acc;
}

// ---- kernel 4: MFMA GEMM, dbuf BK=32, counted-vmcnt pipeline ----
__global__ __launch_bounds__(256, 3) void k_gemm2(
        const float*  __restrict__ xv,    // Xflat [131072][512] f32
        const ushort* __restrict__ abt,   // A^T BK=32 images [4][16][8KB]
        const float*  __restrict__ amean, // A f32 [j][o]
        float* __restrict__ p2,           // [256][4][512]
        float* __restrict__ yvar)         // [256][512][512]
{
    __shared__ float  ldsX[2][4096];      // 2 x 16KB: 128 rows x 32 f32 (128B rows)
    __shared__ ushort ldsA[2][4096];      // 2 x 8KB:  64 superrows x 128B
    __shared__ float  red[2][128];

    int t = threadIdx.x;
    int lane = t & 63;
    int wave = t >> 6;
    int wm = wave >> 1, wn = wave & 1;

    int bid = blockIdx.x;
    int swz = (bid & 7) * 512 + (bid >> 3);   // bijective XCD swizzle (4096%8==0)
    int mtile = swz >> 2;                     // 0..1023
    int ntile = swz & 3;
    int n0 = ntile * 128;
    long m0 = (long)mtile * 128;
    int msub = mtile & 3;
    int b = mtile >> 2;

    f32x4 acc[4][4];
    #pragma unroll
    for (int a = 0; a < 4; ++a)
        #pragma unroll
        for (int bq = 0; bq < 4; ++bq)
            acc[a][bq] = (f32x4){0.f, 0.f, 0.f, 0.f};

    // X stage source (pre-swizzled): instr q, lane l -> LDS row wave*32+q*8+(l>>3),
    // phys chunk l&7 holds logical f32-quad (l&7)^(l>>3)
    const float* xs0 = xv + (m0 + wave * 32 + (lane >> 3)) * 512
                       + ((lane & 7) ^ (lane >> 3)) * 4;
    // A stage: linear copy of image bytes
    const char* as0 = (const char*)abt + (long)ntile * 131072
                      + wave * 2048 + lane * 16;

    auto stage = [&](int buf, int ks) {
        char* xd = (char*)(&ldsX[buf][0]) + wave * 4096;
        const float* sx = xs0 + ks * 32;
        #pragma unroll
        for (int q = 0; q < 4; ++q)
            gload16(sx + q * 8 * 512, xd + q * 1024);
        char* ad = (char*)(&ldsA[buf][0]) + wave * 2048;
        const char* sa = as0 + (long)ks * 8192;
        gload16(sa, ad);
        gload16(sa + 1024, ad + 1024);
    };

    auto compute = [&](int buf) {
        bf16x8 af[4], bfr[4];
        int g = lane >> 4;                    // 0..3: K-octet
        #pragma unroll
        for (int nf = 0; nf < 4; ++nf) {
            int r = wn * 64 + nf * 16 + (lane & 15);
            int s = r >> 1;
            int chunk = (((r & 1) << 2) | g) ^ (s & 7);
            bfr[nf] = *(const bf16x8*)((const char*)(&ldsA[buf][0])
                                       + s * 128 + (chunk << 4));
        }
        #pragma unroll
        for (int mf = 0; mf < 4; ++mf) {
            int r = wm * 64 + mf * 16 + (lane & 15);
            int sw = r & 7;
            const char* bx = (const char*)(&ldsX[buf][0]) + r * 128;
            f32x4 lo = *(const f32x4*)(bx + (((2 * g) ^ sw) << 4));
            f32x4 hi = *(const f32x4*)(bx + (((2 * g + 1) ^ sw) << 4));
            bf16x8 a;
            a[0] = (__bf16)lo[0]; a[1] = (__bf16)lo[1];
            a[2] = (__bf16)lo[2]; a[3] = (__bf16)lo[3];
            a[4] = (__bf16)hi[0]; a[5] = (__bf16)hi[1];
            a[6] = (__bf16)hi[2]; a[7] = (__bf16)hi[3];
            af[mf] = a;
        }
        #pragma unroll
        for (int mf = 0; mf < 4; ++mf)
            #pragma unroll
            for (int nf = 0; nf < 4; ++nf)
                acc[mf][nf] = __builtin_amdgcn_mfma_f32_16x16x32_bf16(
                    af[mf], bfr[nf], acc[mf][nf], 0, 0, 0);
    };

    stage(0, 0);                              // prologue: 6 loads in flight
    int cur = 0;
    #pragma unroll
    for (int ks = 0; ks < 16; ++ks) {
        if (ks < 15) stage(cur ^ 1, ks + 1);  // issue next-tile loads (6/wave)
        if (ks < 15) asm volatile("s_waitcnt vmcnt(6)" ::: "memory");
        else         asm volatile("s_waitcnt vmcnt(0)" ::: "memory");
        __builtin_amdgcn_s_barrier();         // cur buffer staged for all waves
        __builtin_amdgcn_sched_barrier(0);
        compute(cur);
        __builtin_amdgcn_sched_barrier(0);
        __builtin_amdgcn_s_barrier();         // all waves done reading cur
        cur ^= 1;
    }

    // epilogue: weighted colsum  term2_partial[o] = sum_rows A[i,o]*C[i,o]
    #pragma unroll
    for (int nf = 0; nf < 4; ++nf) {
        float p = 0.f;
        int o = n0 + wn * 64 + nf * 16 + (lane & 15);
        #pragma unroll
        for (int mf = 0; mf < 4; ++mf) {
            #pragma unroll
            for (int j = 0; j < 4; ++j) {
                int i = msub * 128 + wm * 64 + mf * 16 + ((lane >> 4) * 4) + j;
                p += acc[mf][nf][j] * amean[i * 512 + o];
            }
        }
        p += __shfl_xor(p, 16, 64);
        p += __shfl_xor(p, 32, 64);
        if (lane < 16) red[wm][wn * 64 + nf * 16 + lane] = p;
    }
    __syncthreads();
    if (t < 128) {
        float v = red[0][t] + red[1][t];
        p2[((long)b * 4 + msub) * 512 + n0 + t] = v;
    }

    // zero-fill this block's disjoint 32-row stripe of y_var[b] (diag written later)
    {
        float* zb = yvar + ((long)b * 512 + msub * 128 + ntile * 32) * 512 + t * 4;
        float4 z = make_float4(0.f, 0.f, 0.f, 0.f);
        #pragma unroll
        for (int q = 0; q < 16; ++q)
            *(float4*)(zb + (long)q * 1024) = z;
    }
}

// ---- kernel 5: ymean = bm + sum(yp); yvar diag = bv + sum(tp) + sum(p2) ----
__global__ void k_final(const float* __restrict__ yp, const float* __restrict__ tp,
                        const float* __restrict__ p2,
                        const float* __restrict__ bm, const float* __restrict__ bv,
                        float* __restrict__ ymean, float* __restrict__ yvar) {
    int idx = blockIdx.x * 256 + threadIdx.x;    // b*512+o
    int b = idx >> 9, o = idx & 511;
    float ym = bm[o], t1 = bv[o];
    #pragma unroll
    for (int ic = 0; ic < 8; ++ic) {
        ym += yp[((long)ic * 256 + b) * 512 + o];
        t1 += tp[((long)ic * 256 + b) * 512 + o];
    }
    long pb = (long)b * 2048 + o;
    t1 += p2[pb] + p2[pb + 512] + p2[pb + 1024] + p2[pb + 1536];
    ymean[idx] = ym;
    yvar[(long)idx * 512 + o] = t1;
}

extern "C" void kernel_launch(void* const* d_in, const int* in_sizes, int n_in,
                              void* d_out, int out_size, void* d_ws, size_t ws_size,
                              hipStream_t stream) {
    const float* x_mean = (const float*)d_in[0];
    const float* x_var  = (const float*)d_in[1];
    const float* A_mean = (const float*)d_in[2];
    const float* A_var  = (const float*)d_in[3];
    const float* b_mean = (const float*)d_in[4];
    const float* b_var  = (const float*)d_in[5];

    float* ymean = (float*)d_out;                  // [256,512]
    float* yvar  = (float*)d_out + 131072;         // [256,512,512]

    char* ws = (char*)d_ws;
    ushort* abt = (ushort*)ws;                          // 512 KB (A^T BK=32 images)
    float*  p2  = (float*)(ws + 512 * 1024);            // [256,4,512]   2 MB
    float*  yp  = (float*)(ws + 2560 * 1024);           // [8,256,512]   4 MB
    float*  tp  = (float*)(ws + 6656 * 1024);           // [8,256,512]   4 MB
    float*  xx  = (float*)(ws + 10752 * 1024);          // [256,512]     512 KB

    k_prep_at<<<128, 256, 0, stream>>>(A_mean, abt);
    k_diag<<<512, 256, 0, stream>>>(x_var, x_mean, xx);
    k_t1<<<2048, 256, 0, stream>>>(x_mean, xx, A_mean, A_var, yp, tp);
    k_gemm2<<<4096, 256, 0, stream>>>(x_var, abt, A_mean, p2, yvar);
    k_final<<<512, 256, 0, stream>>>(yp, tp, p2, b_mean, b_var, ymean, yvar);
}